// Round 6
// baseline (219.275 us; speedup 1.0000x reference)
//
#include <hip/hip_runtime.h>
#include <hip/hip_bf16.h>
#include <stdint.h>

// ---------------------------------------------------------------------------
// GumbelQuantizer: z[32768,256] fp32, emb[1024,256] fp32 ->
//   out0 = softmax((-d + gumbel)) @ emb  (straight-through == quantized)
//   out1 = 1.25 * mean((quantized - z)^2)
// Fused flash-attention-style kernel. s_k = 2 z.e_k - |e_k|^2 (row-constant
// -|z|^2 cancels in softmax). Gumbel via exact JAX threefry2x32:
// exp(g) = 1/(-ln u) -> rcp(-log2 u) (global 1/ln2 cancels in softmax).
// Row t pairs with t+16384 so one cipher call yields both elements' bits.
//
// R6: pin register budget. R5's VGPR_Count=64 + FETCH 299MB revealed the
// compiler targeted 8 waves/EU (64 VGPR) and SPILLED the prefetch arrays to
// scratch. amdgpu_waves_per_eu(4,4) pins exactly 4 waves/EU -> 128 VGPRs,
// prefetches stay in registers, 8 loads in flight + hoisted ciphers hide
// L2 latency. Structure otherwise identical to R5 (R2-validated semantics).
// ---------------------------------------------------------------------------

typedef __bf16 bf16x8 __attribute__((ext_vector_type(8)));
typedef float  f32x4  __attribute__((ext_vector_type(4)));

#define MFMA16(A,B,C) __builtin_amdgcn_mfma_f32_16x16x32_bf16((A),(B),(C),0,0,0)

struct TF2 { uint32_t a, b; };

__host__ __device__ constexpr uint32_t rotl32(uint32_t v, int r){ return (v<<r)|(v>>(32-r)); }

// Threefry-2x32, 20 rounds — exact JAX implementation.
__host__ __device__ constexpr TF2 tf2x32(uint32_t k0, uint32_t k1, uint32_t x0, uint32_t x1){
  const uint32_t k2 = k0 ^ k1 ^ 0x1BD11BDAu;
  x0 += k0; x1 += k1;
  x0 += x1; x1 = rotl32(x1,13); x1 ^= x0;
  x0 += x1; x1 = rotl32(x1,15); x1 ^= x0;
  x0 += x1; x1 = rotl32(x1,26); x1 ^= x0;
  x0 += x1; x1 = rotl32(x1, 6); x1 ^= x0;
  x0 += k1; x1 += k2 + 1u;
  x0 += x1; x1 = rotl32(x1,17); x1 ^= x0;
  x0 += x1; x1 = rotl32(x1,29); x1 ^= x0;
  x0 += x1; x1 = rotl32(x1,16); x1 ^= x0;
  x0 += x1; x1 = rotl32(x1,24); x1 ^= x0;
  x0 += k2; x1 += k0 + 2u;
  x0 += x1; x1 = rotl32(x1,13); x1 ^= x0;
  x0 += x1; x1 = rotl32(x1,15); x1 ^= x0;
  x0 += x1; x1 = rotl32(x1,26); x1 ^= x0;
  x0 += x1; x1 = rotl32(x1, 6); x1 ^= x0;
  x0 += k0; x1 += k1 + 3u;
  x0 += x1; x1 = rotl32(x1,17); x1 ^= x0;
  x0 += x1; x1 = rotl32(x1,29); x1 ^= x0;
  x0 += x1; x1 = rotl32(x1,16); x1 ^= x0;
  x0 += x1; x1 = rotl32(x1,24); x1 ^= x0;
  x0 += k1; x1 += k2 + 4u;
  x0 += x1; x1 = rotl32(x1,13); x1 ^= x0;
  x0 += x1; x1 = rotl32(x1,15); x1 ^= x0;
  x0 += x1; x1 = rotl32(x1,26); x1 ^= x0;
  x0 += x1; x1 = rotl32(x1, 6); x1 ^= x0;
  x0 += k2; x1 += k0 + 5u;
  return {x0, x1};
}

// gkey = fold_in(key(0), 1) = threefry((0,0), (0,1)) — compile-time.
constexpr TF2 GKEY = tf2x32(0u, 0u, 0u, 1u);

__device__ __forceinline__ unsigned short f2bf(float f){
  __bf16 h = (__bf16)f;
  return __builtin_bit_cast(unsigned short, h);
}

// exp(gumbel) up to a global constant: 1/(-log2 u), u = JAX uniform(tiny,1)
__device__ __forceinline__ float gumbel_w(uint32_t bits){
  float uf = __uint_as_float((bits >> 9) | 0x3f800000u) - 1.0f;
  float u  = fmaxf(uf, 1.17549435e-38f);   // == max(tiny, uf*(1-tiny)+tiny) in fp32
  return __builtin_amdgcn_rcpf(-__log2f(u));
}

// ---------------------------------------------------------------------------
// Prep: bf16 E [1024][256], bf16 E^T [256][1024], |e_k|^2 fp32 [1024]
// ---------------------------------------------------------------------------
__global__ void gq_prep(const float* __restrict__ emb, unsigned short* __restrict__ Eb,
                        unsigned short* __restrict__ ETb, float* __restrict__ enorm)
{
  const int r = blockIdx.x;       // 1024 emb rows
  const int t = threadIdx.x;      // 256 threads = one row
  float e = emb[r*256 + t];
  unsigned short h = f2bf(e);
  Eb[r*256 + t] = h;
  ETb[t*1024 + r] = h;
  float sq = e*e;
  #pragma unroll
  for (int o = 32; o > 0; o >>= 1) sq += __shfl_down(sq, o);
  __shared__ float ws4[4];
  if ((t & 63) == 0) ws4[t >> 6] = sq;
  __syncthreads();
  if (t == 0) enorm[r] = ws4[0] + ws4[1] + ws4[2] + ws4[3];
}

// ---------------------------------------------------------------------------
// Main fused kernel: 512 blocks x 512 threads (8 waves), 2 blocks/CU.
// Block b owns z rows [b*32, b*32+32) (G0) and +16384 (G1) — threefry pairs.
// LDS: zb  = bf16 z [64][256] XOR-swizzled        32768 B
//      Pl  = bf16 P [2][64][128] XOR-swizzled     32768 B (double-buffered)
// Wave w owns emb-col stripe w*16 within each 128-wide k-tile (matmul 1)
// and d-cols [w*32, w*32+32) of the output (matmul 2).
// ---------------------------------------------------------------------------
__global__ __launch_bounds__(512)
__attribute__((amdgpu_waves_per_eu(4, 4)))   // pin 4 waves/EU -> 128 VGPR budget
void gq_main(
    const float* __restrict__ z, const unsigned short* __restrict__ Eb,
    const unsigned short* __restrict__ ETb, const float* __restrict__ enorm,
    float* __restrict__ out, float* __restrict__ partials)
{
  __shared__ __align__(16) unsigned char sm[32768 + 32768];
  unsigned char* zb  = sm;                             // bf16 z, swizzled
  unsigned char* Pl0 = sm + 32768;                     // bf16 P, dbuf, swizzled
  float* denomW = (float*)(sm + 32768);                // reuse: [8][64]
  float* denomF = (float*)(sm + 32768 + 2048);         // [64]
  float* lsumW  = (float*)(sm + 32768 + 2048 + 256);   // [8]

  const int tid  = threadIdx.x;
  const int lane = tid & 63;
  const int wv   = tid >> 6;        // wave 0..7
  const int col  = lane & 15;
  const int hi   = lane >> 4;       // 0..3
  const int b32  = blockIdx.x * 32;

  // ---- stage z: fp32 -> bf16 swizzled LDS ----
  #pragma unroll
  for (int j = 0; j < 8; ++j) {
    int lin = j*512 + tid;              // 0..4095 float4s
    int row = lin >> 6;                 // 0..63
    int c4  = lin & 63;
    int grow = (row < 32) ? (b32 + row) : (16384 + b32 + row - 32);
    float4 v = *(reinterpret_cast<const float4*>(z + (size_t)grow*256) + c4);
    uint32_t lo = (uint32_t)f2bf(v.x) | ((uint32_t)f2bf(v.y) << 16);
    uint32_t h2 = (uint32_t)f2bf(v.z) | ((uint32_t)f2bf(v.w) << 16);
    int boff = (row*512 + c4*8) ^ ((row & 7) << 4);
    uint32_t* p = reinterpret_cast<uint32_t*>(zb + boff);
    p[0] = lo; p[1] = h2;
  }
  __syncthreads();

  f32x4 accQ[4][2] = {};      // Q accumulator: 4 row-tiles x 2 d-col-tiles
  float dn[4][4] = {};        // denominator partials per (row-tile, reg)
  float lsum = 0.0f;

  #pragma unroll 1
  for (int kt = 0; kt < 8; ++kt) {
    const int ke0 = kt*128 + wv*16;     // this wave's emb-row base
    unsigned char* Pl = Pl0 + (kt & 1)*16384;

    // ============ region 1: m1-B prefetch + ciphers + m1 MFMAs ============
    // All independent chains in one basic block: 8 global loads in flight,
    // ~1100 cycles of threefry VALU for the scheduler to hide them under,
    // then 32 MFMAs whose A-side comes from LDS.
    const unsigned short* ebase = Eb + (size_t)(ke0 + col)*256 + hi*8;
    bf16x8 mb[8];
    #pragma unroll
    for (int kk = 0; kk < 8; ++kk)
      mb[kk] = *reinterpret_cast<const bf16x8*>(ebase + kk*32);

    float enk = enorm[ke0 + col];

    TF2 c[2][4];                       // ciphers: zero data dependencies
    #pragma unroll
    for (int rt = 0; rt < 2; ++rt) {
      #pragma unroll
      for (int rg = 0; rg < 4; ++rg) {
        int rowL = rt*16 + hi*4 + rg;                       // G0 LDS row (0..31)
        uint32_t idx = (uint32_t)(b32 + rowL)*1024u + (uint32_t)(ke0 + col);
        c[rt][rg] = tf2x32(GKEY.a, GKEY.b, idx, idx + (1u<<24)); // (t, t+16384)
      }
    }

    f32x4 aS[4] = {};
    __builtin_amdgcn_s_setprio(1);
    #pragma unroll
    for (int kk = 0; kk < 8; ++kk) {
      #pragma unroll
      for (int rt = 0; rt < 4; ++rt) {
        int arow = rt*16 + col;
        int aoff = (arow*512 + kk*64 + hi*16) ^ ((arow & 7) << 4);
        bf16x8 af = *reinterpret_cast<const bf16x8*>(zb + aoff);
        aS[rt] = MFMA16(af, mb[kk], aS[rt]);
      }
    }
    __builtin_amdgcn_s_setprio(0);

    // ============ region 2: m2-B prefetch + exp/pack/store P ============
    const unsigned short* etb0 = ETb + (size_t)(wv*32 + col)*1024 + kt*128 + hi*8;
    const unsigned short* etb1 = etb0 + 16*1024;
    bf16x8 nb[8];
    #pragma unroll
    for (int kk = 0; kk < 4; ++kk) {
      nb[kk]   = *reinterpret_cast<const bf16x8*>(etb0 + kk*32);
      nb[kk+4] = *reinterpret_cast<const bf16x8*>(etb1 + kk*32);
    }

    #pragma unroll
    for (int rt = 0; rt < 2; ++rt) {
      #pragma unroll
      for (int rg = 0; rg < 4; ++rg) {
        int rowL = rt*16 + hi*4 + rg;
        float p0 = __expf(2.0f*aS[rt  ][rg] - enk) * gumbel_w(c[rt][rg].a);
        float p1 = __expf(2.0f*aS[rt+2][rg] - enk) * gumbel_w(c[rt][rg].b);
        dn[rt  ][rg] += p0;
        dn[rt+2][rg] += p1;
        int cl2  = (wv*16 + col)*2;
        int rowH = rowL + 32;
        *(unsigned short*)(Pl + ((rowL*256 + cl2) ^ ((rowL&7)<<4))) = f2bf(p0);
        *(unsigned short*)(Pl + ((rowH*256 + cl2) ^ ((rowH&7)<<4))) = f2bf(p1);
      }
    }
    __syncthreads();

    // ============ region 3: m2 MFMAs (no global loads) ============
    __builtin_amdgcn_s_setprio(1);
    #pragma unroll
    for (int kk = 0; kk < 4; ++kk) {
      #pragma unroll
      for (int rt = 0; rt < 4; ++rt) {
        int prow = rt*16 + col;
        int poff = (prow*256 + kk*64 + hi*16) ^ ((prow&7)<<4);
        bf16x8 af = *reinterpret_cast<const bf16x8*>(Pl + poff);
        accQ[rt][0] = MFMA16(af, nb[kk],   accQ[rt][0]);
        accQ[rt][1] = MFMA16(af, nb[kk+4], accQ[rt][1]);
      }
    }
    __builtin_amdgcn_s_setprio(0);
    // no second barrier: next iteration writes the other P buffer
  }
  __syncthreads();   // protect reduction-scratch reuse of Pl

  // ---- denominator: reduce over 16 lanes (this wave's cols), then 8 waves ----
  #pragma unroll
  for (int rt = 0; rt < 4; ++rt)
    #pragma unroll
    for (int rg = 0; rg < 4; ++rg) {
      float v = dn[rt][rg];
      v += __shfl_xor(v, 1);
      v += __shfl_xor(v, 2);
      v += __shfl_xor(v, 4);
      v += __shfl_xor(v, 8);
      dn[rt][rg] = v;
    }
  if (col == 0) {
    #pragma unroll
    for (int rt = 0; rt < 4; ++rt)
      #pragma unroll
      for (int rg = 0; rg < 4; ++rg)
        denomW[wv*64 + rt*16 + hi*4 + rg] = dn[rt][rg];
  }
  __syncthreads();
  if (tid < 64) {
    float s = 0.f;
    #pragma unroll
    for (int w2 = 0; w2 < 8; ++w2) s += denomW[w2*64 + tid];
    denomF[tid] = __builtin_amdgcn_rcpf(s);
  }
  __syncthreads();

  // ---- epilogue: normalize, write out0, accumulate loss partial ----
  // z re-read from global (L3-resident) replaces an fp32 LDS copy.
  #pragma unroll
  for (int rt = 0; rt < 4; ++rt) {
    #pragma unroll
    for (int rg = 0; rg < 4; ++rg) {
      int row = rt*16 + hi*4 + rg;
      float rd = denomF[row];
      int grow = (row < 32) ? (b32 + row) : (16384 + b32 + row - 32);
      float* orow = out + (size_t)grow*256;
      const float* zrow = z + (size_t)grow*256;
      #pragma unroll
      for (int ct = 0; ct < 2; ++ct) {
        int d = wv*32 + ct*16 + col;
        float q  = accQ[rt][ct][rg] * rd;
        float zv = zrow[d];
        float df = q - zv;
        orow[d] = zv + df;          // straight-through value == quantized
        lsum += df*df;
      }
    }
  }
  #pragma unroll
  for (int o = 32; o > 0; o >>= 1) lsum += __shfl_down(lsum, o);
  if (lane == 0) lsumW[wv] = lsum;
  __syncthreads();
  if (tid == 0) {
    float s = 0.f;
    #pragma unroll
    for (int w2 = 0; w2 < 8; ++w2) s += lsumW[w2];
    partials[blockIdx.x] = s;
  }
}

// ---------------------------------------------------------------------------
// Final: loss = 1.25 * sum(partials) / 2^23
// ---------------------------------------------------------------------------
__global__ void gq_final(const float* __restrict__ partials, float* __restrict__ out)
{
  const int t = threadIdx.x;   // 512
  float v = partials[t];
  #pragma unroll
  for (int o = 32; o > 0; o >>= 1) v += __shfl_down(v, o);
  __shared__ float ws8[8];
  if ((t & 63) == 0) ws8[t >> 6] = v;
  __syncthreads();
  if (t == 0) {
    float s = 0.f;
    #pragma unroll
    for (int i = 0; i < 8; ++i) s += ws8[i];
    out[8388608] = 1.25f * s * (1.0f / 8388608.0f);
  }
}

extern "C" void kernel_launch(void* const* d_in, const int* in_sizes, int n_in,
                              void* d_out, int out_size, void* d_ws, size_t ws_size,
                              hipStream_t stream)
{
  const float* z   = (const float*)d_in[0];   // [32,1024,256]
  const float* emb = (const float*)d_in[1];   // [1024,256]
  float* out = (float*)d_out;                 // 8388608 + 1
  char* ws = (char*)d_ws;
  unsigned short* Eb  = (unsigned short*)ws;               // 524288 B
  unsigned short* ETb = (unsigned short*)(ws + 524288);    // 524288 B
  float* enorm    = (float*)(ws + 1048576);                // 4096 B
  float* partials = (float*)(ws + 1048576 + 4096);         // 2048 B

  gq_prep<<<1024, 256, 0, stream>>>(emb, Eb, ETb, enorm);
  gq_main<<<512, 512, 0, stream>>>(z, Eb, ETb, enorm, out, partials);
  gq_final<<<1, 512, 0, stream>>>(partials, out);
}

// Round 7
// 92.501 us; speedup vs baseline: 2.3705x; 2.3705x over previous
//
#include <hip/hip_runtime.h>
#include <hip/hip_bf16.h>
#include <stdint.h>

// ---------------------------------------------------------------------------
// GumbelQuantizer: z[32768,256] fp32, emb[1024,256] fp32 ->
//   out0 = softmax((-d + gumbel)) @ emb  (straight-through == quantized)
//   out1 = 1.25 * mean((quantized - z)^2)
// Fused flash-attention-style kernel. s_k = 2 z.e_k - |e_k|^2 (row-constant
// -|z|^2 cancels in softmax). Gumbel via exact JAX threefry2x32:
// exp(g) = 1/(-ln u) -> rcp(-log2 u) (global 1/ln2 cancels in softmax).
// Row t pairs with t+16384 so one cipher call yields both elements' bits.
//
// R7: fix the register budget for real. Empirical table (R1-R6): hipcc gives
// a 64-VGPR cap for __launch_bounds__(512,4) (R5/R6 spilled the prefetch
// arrays -> +200MB scratch HBM traffic), but a 128-reg cap for (512,2) --
// R1 used 88 without spill. LDS (64KiB/block) already caps residency at
// 2 blocks/CU, so (512,2) loses nothing. Structure identical to R5:
//   region1: prefetch all m1 B-frags + 8 threefry ciphers + m1 MFMAs.
//   region2: prefetch all m2 B-frags under exp/pack/store-P VALU.
//   region3 (post-barrier): m2 = ds_read + MFMA only.
// ---------------------------------------------------------------------------

typedef __bf16 bf16x8 __attribute__((ext_vector_type(8)));
typedef float  f32x4  __attribute__((ext_vector_type(4)));

#define MFMA16(A,B,C) __builtin_amdgcn_mfma_f32_16x16x32_bf16((A),(B),(C),0,0,0)

struct TF2 { uint32_t a, b; };

__host__ __device__ constexpr uint32_t rotl32(uint32_t v, int r){ return (v<<r)|(v>>(32-r)); }

// Threefry-2x32, 20 rounds — exact JAX implementation.
__host__ __device__ constexpr TF2 tf2x32(uint32_t k0, uint32_t k1, uint32_t x0, uint32_t x1){
  const uint32_t k2 = k0 ^ k1 ^ 0x1BD11BDAu;
  x0 += k0; x1 += k1;
  x0 += x1; x1 = rotl32(x1,13); x1 ^= x0;
  x0 += x1; x1 = rotl32(x1,15); x1 ^= x0;
  x0 += x1; x1 = rotl32(x1,26); x1 ^= x0;
  x0 += x1; x1 = rotl32(x1, 6); x1 ^= x0;
  x0 += k1; x1 += k2 + 1u;
  x0 += x1; x1 = rotl32(x1,17); x1 ^= x0;
  x0 += x1; x1 = rotl32(x1,29); x1 ^= x0;
  x0 += x1; x1 = rotl32(x1,16); x1 ^= x0;
  x0 += x1; x1 = rotl32(x1,24); x1 ^= x0;
  x0 += k2; x1 += k0 + 2u;
  x0 += x1; x1 = rotl32(x1,13); x1 ^= x0;
  x0 += x1; x1 = rotl32(x1,15); x1 ^= x0;
  x0 += x1; x1 = rotl32(x1,26); x1 ^= x0;
  x0 += x1; x1 = rotl32(x1, 6); x1 ^= x0;
  x0 += k0; x1 += k1 + 3u;
  x0 += x1; x1 = rotl32(x1,17); x1 ^= x0;
  x0 += x1; x1 = rotl32(x1,29); x1 ^= x0;
  x0 += x1; x1 = rotl32(x1,16); x1 ^= x0;
  x0 += x1; x1 = rotl32(x1,24); x1 ^= x0;
  x0 += k1; x1 += k2 + 4u;
  x0 += x1; x1 = rotl32(x1,13); x1 ^= x0;
  x0 += x1; x1 = rotl32(x1,15); x1 ^= x0;
  x0 += x1; x1 = rotl32(x1,26); x1 ^= x0;
  x0 += x1; x1 = rotl32(x1, 6); x1 ^= x0;
  x0 += k2; x1 += k0 + 5u;
  return {x0, x1};
}

// gkey = fold_in(key(0), 1) = threefry((0,0), (0,1)) — compile-time.
constexpr TF2 GKEY = tf2x32(0u, 0u, 0u, 1u);

__device__ __forceinline__ unsigned short f2bf(float f){
  __bf16 h = (__bf16)f;
  return __builtin_bit_cast(unsigned short, h);
}

// exp(gumbel) up to a global constant: 1/(-log2 u), u = JAX uniform(tiny,1)
__device__ __forceinline__ float gumbel_w(uint32_t bits){
  float uf = __uint_as_float((bits >> 9) | 0x3f800000u) - 1.0f;
  float u  = fmaxf(uf, 1.17549435e-38f);   // == max(tiny, uf*(1-tiny)+tiny) in fp32
  return __builtin_amdgcn_rcpf(-__log2f(u));
}

// ---------------------------------------------------------------------------
// Prep: bf16 E [1024][256], bf16 E^T [256][1024], |e_k|^2 fp32 [1024]
// ---------------------------------------------------------------------------
__global__ void gq_prep(const float* __restrict__ emb, unsigned short* __restrict__ Eb,
                        unsigned short* __restrict__ ETb, float* __restrict__ enorm)
{
  const int r = blockIdx.x;       // 1024 emb rows
  const int t = threadIdx.x;      // 256 threads = one row
  float e = emb[r*256 + t];
  unsigned short h = f2bf(e);
  Eb[r*256 + t] = h;
  ETb[t*1024 + r] = h;
  float sq = e*e;
  #pragma unroll
  for (int o = 32; o > 0; o >>= 1) sq += __shfl_down(sq, o);
  __shared__ float ws4[4];
  if ((t & 63) == 0) ws4[t >> 6] = sq;
  __syncthreads();
  if (t == 0) enorm[r] = ws4[0] + ws4[1] + ws4[2] + ws4[3];
}

// ---------------------------------------------------------------------------
// Main fused kernel: 512 blocks x 512 threads (8 waves), 2 blocks/CU.
// Block b owns z rows [b*32, b*32+32) (G0) and +16384 (G1) — threefry pairs.
// LDS: zb  = bf16 z [64][256] XOR-swizzled        32768 B
//      Pl  = bf16 P [2][64][128] XOR-swizzled     32768 B (double-buffered)
// Wave w owns emb-col stripe w*16 within each 128-wide k-tile (matmul 1)
// and d-cols [w*32, w*32+32) of the output (matmul 2).
// ---------------------------------------------------------------------------
__global__ __launch_bounds__(512, 2)   // empirically: 128-VGPR budget, no spill
void gq_main(
    const float* __restrict__ z, const unsigned short* __restrict__ Eb,
    const unsigned short* __restrict__ ETb, const float* __restrict__ enorm,
    float* __restrict__ out, float* __restrict__ partials)
{
  __shared__ __align__(16) unsigned char sm[32768 + 32768];
  unsigned char* zb  = sm;                             // bf16 z, swizzled
  unsigned char* Pl0 = sm + 32768;                     // bf16 P, dbuf, swizzled
  float* denomW = (float*)(sm + 32768);                // reuse: [8][64]
  float* denomF = (float*)(sm + 32768 + 2048);         // [64]
  float* lsumW  = (float*)(sm + 32768 + 2048 + 256);   // [8]

  const int tid  = threadIdx.x;
  const int lane = tid & 63;
  const int wv   = tid >> 6;        // wave 0..7
  const int col  = lane & 15;
  const int hi   = lane >> 4;       // 0..3
  const int b32  = blockIdx.x * 32;

  // ---- stage z: fp32 -> bf16 swizzled LDS ----
  #pragma unroll
  for (int j = 0; j < 8; ++j) {
    int lin = j*512 + tid;              // 0..4095 float4s
    int row = lin >> 6;                 // 0..63
    int c4  = lin & 63;
    int grow = (row < 32) ? (b32 + row) : (16384 + b32 + row - 32);
    float4 v = *(reinterpret_cast<const float4*>(z + (size_t)grow*256) + c4);
    uint32_t lo = (uint32_t)f2bf(v.x) | ((uint32_t)f2bf(v.y) << 16);
    uint32_t h2 = (uint32_t)f2bf(v.z) | ((uint32_t)f2bf(v.w) << 16);
    int boff = (row*512 + c4*8) ^ ((row & 7) << 4);
    uint32_t* p = reinterpret_cast<uint32_t*>(zb + boff);
    p[0] = lo; p[1] = h2;
  }
  __syncthreads();

  f32x4 accQ[4][2] = {};      // Q accumulator: 4 row-tiles x 2 d-col-tiles
  float dn[4][4] = {};        // denominator partials per (row-tile, reg)
  float lsum = 0.0f;

  #pragma unroll 1
  for (int kt = 0; kt < 8; ++kt) {
    const int ke0 = kt*128 + wv*16;     // this wave's emb-row base
    unsigned char* Pl = Pl0 + (kt & 1)*16384;

    // ============ region 1: m1-B prefetch + ciphers + m1 MFMAs ============
    // All independent chains in one basic block: 8 global loads in flight,
    // ~1100 cycles of threefry VALU for the scheduler to hide them under,
    // then 32 MFMAs whose A-side comes from LDS.
    const unsigned short* ebase = Eb + (size_t)(ke0 + col)*256 + hi*8;
    bf16x8 mb[8];
    #pragma unroll
    for (int kk = 0; kk < 8; ++kk)
      mb[kk] = *reinterpret_cast<const bf16x8*>(ebase + kk*32);

    float enk = enorm[ke0 + col];

    TF2 c[2][4];                       // ciphers: zero data dependencies
    #pragma unroll
    for (int rt = 0; rt < 2; ++rt) {
      #pragma unroll
      for (int rg = 0; rg < 4; ++rg) {
        int rowL = rt*16 + hi*4 + rg;                       // G0 LDS row (0..31)
        uint32_t idx = (uint32_t)(b32 + rowL)*1024u + (uint32_t)(ke0 + col);
        c[rt][rg] = tf2x32(GKEY.a, GKEY.b, idx, idx + (1u<<24)); // (t, t+16384)
      }
    }

    f32x4 aS[4] = {};
    __builtin_amdgcn_s_setprio(1);
    #pragma unroll
    for (int kk = 0; kk < 8; ++kk) {
      #pragma unroll
      for (int rt = 0; rt < 4; ++rt) {
        int arow = rt*16 + col;
        int aoff = (arow*512 + kk*64 + hi*16) ^ ((arow & 7) << 4);
        bf16x8 af = *reinterpret_cast<const bf16x8*>(zb + aoff);
        aS[rt] = MFMA16(af, mb[kk], aS[rt]);
      }
    }
    __builtin_amdgcn_s_setprio(0);

    // ============ region 2: m2-B prefetch + exp/pack/store P ============
    const unsigned short* etb0 = ETb + (size_t)(wv*32 + col)*1024 + kt*128 + hi*8;
    const unsigned short* etb1 = etb0 + 16*1024;
    bf16x8 nb[8];
    #pragma unroll
    for (int kk = 0; kk < 4; ++kk) {
      nb[kk]   = *reinterpret_cast<const bf16x8*>(etb0 + kk*32);
      nb[kk+4] = *reinterpret_cast<const bf16x8*>(etb1 + kk*32);
    }

    #pragma unroll
    for (int rt = 0; rt < 2; ++rt) {
      #pragma unroll
      for (int rg = 0; rg < 4; ++rg) {
        int rowL = rt*16 + hi*4 + rg;
        float p0 = __expf(2.0f*aS[rt  ][rg] - enk) * gumbel_w(c[rt][rg].a);
        float p1 = __expf(2.0f*aS[rt+2][rg] - enk) * gumbel_w(c[rt][rg].b);
        dn[rt  ][rg] += p0;
        dn[rt+2][rg] += p1;
        int cl2  = (wv*16 + col)*2;
        int rowH = rowL + 32;
        *(unsigned short*)(Pl + ((rowL*256 + cl2) ^ ((rowL&7)<<4))) = f2bf(p0);
        *(unsigned short*)(Pl + ((rowH*256 + cl2) ^ ((rowH&7)<<4))) = f2bf(p1);
      }
    }
    __syncthreads();

    // ============ region 3: m2 MFMAs (no global loads) ============
    __builtin_amdgcn_s_setprio(1);
    #pragma unroll
    for (int kk = 0; kk < 4; ++kk) {
      #pragma unroll
      for (int rt = 0; rt < 4; ++rt) {
        int prow = rt*16 + col;
        int poff = (prow*256 + kk*64 + hi*16) ^ ((prow&7)<<4);
        bf16x8 af = *reinterpret_cast<const bf16x8*>(Pl + poff);
        accQ[rt][0] = MFMA16(af, nb[kk],   accQ[rt][0]);
        accQ[rt][1] = MFMA16(af, nb[kk+4], accQ[rt][1]);
      }
    }
    __builtin_amdgcn_s_setprio(0);
    // no second barrier: next iteration writes the other P buffer
  }
  __syncthreads();   // protect reduction-scratch reuse of Pl

  // ---- denominator: reduce over 16 lanes (this wave's cols), then 8 waves ----
  #pragma unroll
  for (int rt = 0; rt < 4; ++rt)
    #pragma unroll
    for (int rg = 0; rg < 4; ++rg) {
      float v = dn[rt][rg];
      v += __shfl_xor(v, 1);
      v += __shfl_xor(v, 2);
      v += __shfl_xor(v, 4);
      v += __shfl_xor(v, 8);
      dn[rt][rg] = v;
    }
  if (col == 0) {
    #pragma unroll
    for (int rt = 0; rt < 4; ++rt)
      #pragma unroll
      for (int rg = 0; rg < 4; ++rg)
        denomW[wv*64 + rt*16 + hi*4 + rg] = dn[rt][rg];
  }
  __syncthreads();
  if (tid < 64) {
    float s = 0.f;
    #pragma unroll
    for (int w2 = 0; w2 < 8; ++w2) s += denomW[w2*64 + tid];
    denomF[tid] = __builtin_amdgcn_rcpf(s);
  }
  __syncthreads();

  // ---- epilogue: normalize, write out0, accumulate loss partial ----
  // z re-read from global (L3-resident) replaces an fp32 LDS copy.
  #pragma unroll
  for (int rt = 0; rt < 4; ++rt) {
    #pragma unroll
    for (int rg = 0; rg < 4; ++rg) {
      int row = rt*16 + hi*4 + rg;
      float rd = denomF[row];
      int grow = (row < 32) ? (b32 + row) : (16384 + b32 + row - 32);
      float* orow = out + (size_t)grow*256;
      const float* zrow = z + (size_t)grow*256;
      #pragma unroll
      for (int ct = 0; ct < 2; ++ct) {
        int d = wv*32 + ct*16 + col;
        float q  = accQ[rt][ct][rg] * rd;
        float zv = zrow[d];
        float df = q - zv;
        orow[d] = zv + df;          // straight-through value == quantized
        lsum += df*df;
      }
    }
  }
  #pragma unroll
  for (int o = 32; o > 0; o >>= 1) lsum += __shfl_down(lsum, o);
  if (lane == 0) lsumW[wv] = lsum;
  __syncthreads();
  if (tid == 0) {
    float s = 0.f;
    #pragma unroll
    for (int w2 = 0; w2 < 8; ++w2) s += lsumW[w2];
    partials[blockIdx.x] = s;
  }
}

// ---------------------------------------------------------------------------
// Final: loss = 1.25 * sum(partials) / 2^23
// ---------------------------------------------------------------------------
__global__ void gq_final(const float* __restrict__ partials, float* __restrict__ out)
{
  const int t = threadIdx.x;   // 512
  float v = partials[t];
  #pragma unroll
  for (int o = 32; o > 0; o >>= 1) v += __shfl_down(v, o);
  __shared__ float ws8[8];
  if ((t & 63) == 0) ws8[t >> 6] = v;
  __syncthreads();
  if (t == 0) {
    float s = 0.f;
    #pragma unroll
    for (int i = 0; i < 8; ++i) s += ws8[i];
    out[8388608] = 1.25f * s * (1.0f / 8388608.0f);
  }
}

extern "C" void kernel_launch(void* const* d_in, const int* in_sizes, int n_in,
                              void* d_out, int out_size, void* d_ws, size_t ws_size,
                              hipStream_t stream)
{
  const float* z   = (const float*)d_in[0];   // [32,1024,256]
  const float* emb = (const float*)d_in[1];   // [1024,256]
  float* out = (float*)d_out;                 // 8388608 + 1
  char* ws = (char*)d_ws;
  unsigned short* Eb  = (unsigned short*)ws;               // 524288 B
  unsigned short* ETb = (unsigned short*)(ws + 524288);    // 524288 B
  float* enorm    = (float*)(ws + 1048576);                // 4096 B
  float* partials = (float*)(ws + 1048576 + 4096);         // 2048 B

  gq_prep<<<1024, 256, 0, stream>>>(emb, Eb, ETb, enorm);
  gq_main<<<512, 512, 0, stream>>>(z, Eb, ETb, enorm, out, partials);
  gq_final<<<1, 512, 0, stream>>>(partials, out);
}